// Round 9
// baseline (37.275 us; speedup 1.0000x reference)
//
#include <hip/hip_runtime.h>
#include <hip/hip_bf16.h>

#define IN_F  4096
#define OUT_F 11008

typedef _Float16 half8 __attribute__((ext_vector_type(8)));
typedef _Float16 half4 __attribute__((ext_vector_type(4)));
typedef __fp16   fp16x2 __attribute__((ext_vector_type(2)));
typedef float    f32x4 __attribute__((ext_vector_type(4)));
typedef int      i32x4 __attribute__((ext_vector_type(4)));

// d_ws layout (256 KB): prepacked x A-fragments (fp16).
// For k-step s (0..127), token-half h (0..1), lane l (0..63):
//   8 halfs at xws + ((s*2 + h)*64 + l)*8
//   element j = x[h*16 + (l&15)][s*32 + (l>>4)*8 + j]
__global__ __launch_bounds__(256, 4)
void prepack_x(const float* __restrict__ x, _Float16* __restrict__ xws) {
    const int idx = blockIdx.x * 256 + threadIdx.x;   // 0..16383
    const int l = idx & 63;
    const int h = (idx >> 6) & 1;
    const int s = idx >> 7;
    const float* src = x + (size_t)(h * 16 + (l & 15)) * IN_F + s * 32 + (l >> 4) * 8;
    half8 v;
    #pragma unroll
    for (int j = 0; j < 8; ++j) v[j] = (_Float16)src[j];
    *(half8*)(xws + (size_t)idx * 8) = v;
}

// Main: block = 16 output channels, 512 threads = 8 waves.
// Wave w owns K slice [w*512, w*512+512) = 8 chunks of 64 k.
//  - weights: COALESCED -> regs (3-deep prefetch rotation: chunk ch+3 issued
//    at end of body ch => ~2.5 bodies (~1100 cy) of latency cover vs ~900 cy
//    HBM) -> cvt_pkrtz fp16 -> wave-private LDS (144B stride) -> ds_read_b128.
//  - x: prepacked fragments, 2-deep (L2-resident, short latency).
//  - no main-loop __syncthreads.
__global__ __launch_bounds__(512, 4)
void dql_main(const int* __restrict__ wq,           // [11008][4096] int32
              const _Float16* __restrict__ xws,     // prepacked fragments
              const float* __restrict__ scale,      // [11008]
              const float* __restrict__ bias,       // [11008]
              float* __restrict__ out)              // [32][11008]
{
    __shared__ __align__(16) _Float16 wlds[8][16][72];  // 144B row stride
    __shared__ float red[8][64][9];

    const int tid  = threadIdx.x;
    const int wid  = tid >> 6;
    const int lane = tid & 63;
    const int c    = lane & 15;           // fragment: channel row / token row
    const int kg   = lane >> 4;           // fragment: k-group (8 k each)
    const int srow = lane >> 2;           // weight staging: row (0..15)
    const int scol = (lane & 3) * 4;      // weight staging: int offset in chunk
    const int obase = blockIdx.x * 16;
    const int kbase = wid * 512;

    const int* wrow = wq + (size_t)(obase + srow) * IN_F + kbase + scol;
    const _Float16* xbase = xws + ((size_t)(wid * 32) * 64 + lane) * 8;

    f32x4 acc0 = {0.f, 0.f, 0.f, 0.f};
    f32x4 acc1 = {0.f, 0.f, 0.f, 0.f};

    i32x4 w[3][4];   // 3-deep W prefetch ring
    i32x4 x[2][4];   // 2-deep X prefetch

    auto LOADW = [&](i32x4* wbuf, int ch) {
        #pragma unroll
        for (int i = 0; i < 4; ++i)
            wbuf[i] = *(const i32x4*)(wrow + ch * 64 + i * 16);
    };
    auto LOADX = [&](i32x4* xbuf, int ch) {
        #pragma unroll
        for (int q = 0; q < 4; ++q)       // q = sub*2 + h
            xbuf[q] = *(const i32x4*)(xbase + (size_t)(ch * 4 + q) * 512);
    };

    // prologue: 3 W chunks + 1 X chunk in flight
    LOADW(w[0], 0); LOADW(w[1], 1); LOADW(w[2], 2);
    LOADX(x[0], 0);

    #pragma unroll
    for (int ch = 0; ch < 8; ++ch) {
        if (ch + 1 < 8) LOADX(x[(ch + 1) & 1], ch + 1);
        // stage chunk ch weights: int -> f32 (exact) -> packed f16 (exact)
        #pragma unroll
        for (int i = 0; i < 4; ++i) {
            union { fp16x2 v2[2]; half4 v4; } u;
            u.v2[0] = __builtin_amdgcn_cvt_pkrtz((float)w[ch % 3][i][0], (float)w[ch % 3][i][1]);
            u.v2[1] = __builtin_amdgcn_cvt_pkrtz((float)w[ch % 3][i][2], (float)w[ch % 3][i][3]);
            *(half4*)&wlds[wid][srow][scol + i * 16] = u.v4;
        }
        // compute: 2 k-steps of 32
        #pragma unroll
        for (int sub = 0; sub < 2; ++sub) {
            half8 wf  = *(half8*)&wlds[wid][c][sub * 32 + kg * 8];
            half8 xf0 = *(half8*)&x[ch & 1][sub * 2 + 0];
            half8 xf1 = *(half8*)&x[ch & 1][sub * 2 + 1];
            acc0 = __builtin_amdgcn_mfma_f32_16x16x32_f16(xf0, wf, acc0, 0, 0, 0);
            acc1 = __builtin_amdgcn_mfma_f32_16x16x32_f16(xf1, wf, acc1, 0, 0, 0);
        }
        // refill the W buffer just consumed with chunk ch+3
        if (ch + 3 < 8) LOADW(w[ch % 3], ch + 3);
    }

    #pragma unroll
    for (int r = 0; r < 4; ++r) {
        red[wid][lane][r]     = acc0[r];
        red[wid][lane][4 + r] = acc1[r];
    }
    __syncthreads();

    // 512 threads: one (lane, slot) each; sum the 8 wave partials.
    const int rlane = tid & 63;
    const int slot  = tid >> 6;          // 0..7 : (token-half h = slot>>2, reg r = slot&3)
    float s = 0.f;
    #pragma unroll
    for (int wv = 0; wv < 8; ++wv) s += red[wv][rlane][slot];

    const int h = slot >> 2;
    const int r = slot & 3;
    const int t = h * 16 + (rlane >> 4) * 4 + r;   // token
    const int o = obase + (rlane & 15);            // output channel

    out[t * OUT_F + o] = s * scale[o] + bias[o];
}

// Fallback if workspace is unavailable: R2 kernel (passed at 70.5 us).
__global__ __launch_bounds__(512, 4)
void dql_fallback(const float* __restrict__ x,
                  const int* __restrict__ wq,
                  const float* __restrict__ scale,
                  const float* __restrict__ bias,
                  float* __restrict__ out)
{
    __shared__ float red[8][64][9];

    const int tid  = threadIdx.x;
    const int wid  = tid >> 6;
    const int lane = tid & 63;
    const int c    = lane & 15;
    const int kg   = lane >> 4;
    const int obase = blockIdx.x * 16;
    const int kwave = wid * 512;

    f32x4 acc0 = {0.f, 0.f, 0.f, 0.f};
    f32x4 acc1 = {0.f, 0.f, 0.f, 0.f};

    const int*   wp  = wq + (size_t)(obase + c) * IN_F + kwave + kg * 8;
    const float* xp0 = x + c * IN_F + kwave + kg * 8;
    const float* xp1 = xp0 + 16 * IN_F;

    #pragma unroll 4
    for (int it = 0; it < 16; ++it) {
        i32x4 b0 = *(const i32x4*)(wp);
        i32x4 b1 = *(const i32x4*)(wp + 4);
        f32x4 a0l = *(const f32x4*)(xp0);
        f32x4 a0h = *(const f32x4*)(xp0 + 4);
        f32x4 a1l = *(const f32x4*)(xp1);
        f32x4 a1h = *(const f32x4*)(xp1 + 4);

        half8 afrag0, afrag1, bfrag;
        #pragma unroll
        for (int j = 0; j < 4; ++j) {
            bfrag[j]      = (_Float16)b0[j];
            bfrag[4 + j]  = (_Float16)b1[j];
            afrag0[j]     = (_Float16)a0l[j];
            afrag0[4 + j] = (_Float16)a0h[j];
            afrag1[j]     = (_Float16)a1l[j];
            afrag1[4 + j] = (_Float16)a1h[j];
        }

        acc0 = __builtin_amdgcn_mfma_f32_16x16x32_f16(afrag0, bfrag, acc0, 0, 0, 0);
        acc1 = __builtin_amdgcn_mfma_f32_16x16x32_f16(afrag1, bfrag, acc1, 0, 0, 0);

        wp  += 32;
        xp0 += 32;
        xp1 += 32;
    }

    #pragma unroll
    for (int r = 0; r < 4; ++r) {
        red[wid][lane][r]     = acc0[r];
        red[wid][lane][4 + r] = acc1[r];
    }
    __syncthreads();

    const int rlane = tid & 63;
    const int slot  = tid >> 6;
    float s = 0.f;
    #pragma unroll
    for (int w = 0; w < 8; ++w) s += red[w][rlane][slot];

    const int h = slot >> 2;
    const int r = slot & 3;
    const int t = h * 16 + (rlane >> 4) * 4 + r;
    const int o = obase + (rlane & 15);

    out[t * OUT_F + o] = s * scale[o] + bias[o];
}

extern "C" void kernel_launch(void* const* d_in, const int* in_sizes, int n_in,
                              void* d_out, int out_size, void* d_ws, size_t ws_size,
                              hipStream_t stream) {
    const float* x     = (const float*)d_in[0];
    const int*   wq    = (const int*)d_in[1];
    const float* scale = (const float*)d_in[2];
    const float* bias  = (const float*)d_in[3];
    float*       out   = (float*)d_out;

    if (ws_size >= (size_t)262144 && d_ws != nullptr) {
        _Float16* xws = (_Float16*)d_ws;
        prepack_x<<<64, 256, 0, stream>>>(x, xws);
        dql_main<<<OUT_F / 16, 512, 0, stream>>>(wq, xws, scale, bias, out);
    } else {
        dql_fallback<<<OUT_F / 16, 512, 0, stream>>>(x, wq, scale, bias, out);
    }
}

// Round 10
// 34.585 us; speedup vs baseline: 1.0778x; 1.0778x over previous
//
#include <hip/hip_runtime.h>
#include <hip/hip_bf16.h>

#define IN_F  4096
#define OUT_F 11008

typedef _Float16 half8 __attribute__((ext_vector_type(8)));
typedef _Float16 half4 __attribute__((ext_vector_type(4)));
typedef __fp16   fp16x2 __attribute__((ext_vector_type(2)));
typedef float    f32x4 __attribute__((ext_vector_type(4)));
typedef int      i32x4 __attribute__((ext_vector_type(4)));

// Single fused kernel. Block: 16 output channels, 512 threads = 8 waves.
// Wave w owns K slice [w*512, w*512+512) = 8 chunks of 64 k.
//  - W: COALESCED (16 rows x dense 256B/chunk) -> regs (2-deep ring) ->
//       cvt_pkrtz fp16 -> wave-private LDS [16][72] -> ds_read_b128 frags.
//  - X: COALESCED (8 rows x dense 128B segments per load-group) -> regs
//       (half-chunk 2-deep) -> cvt_pkrtz fp16 -> wave-private LDS [32][72]
//       -> ds_read_b128 frags. x is L2-resident (512 KB), short latency.
//  - no main-loop __syncthreads, no workspace, one dispatch.
__global__ __launch_bounds__(512, 4)
void dql_fused(const float* __restrict__ x,      // [32][4096] f32 (exact fp16 vals)
               const int* __restrict__ wq,       // [11008][4096] int32 in [-127,127]
               const float* __restrict__ scale,  // [11008]
               const float* __restrict__ bias,   // [11008]
               float* __restrict__ out)          // [32][11008]
{
    __shared__ __align__(16) _Float16 wlds[8][16][72];  // 144B row stride
    __shared__ __align__(16) _Float16 xlds[8][32][72];  // 144B row stride
    __shared__ float red[8][64][9];

    const int tid  = threadIdx.x;
    const int wid  = tid >> 6;
    const int lane = tid & 63;
    const int c    = lane & 15;           // fragment: channel row / token row
    const int kg   = lane >> 4;           // fragment: k-group (8 k each)
    const int srow = lane >> 2;           // W staging: row (0..15)
    const int scol = (lane & 3) * 4;      // W staging: int offset in chunk
    const int xr   = lane >> 3;           // X staging: row-in-group (0..7)
    const int xc   = (lane & 7) * 4;      // X staging: f32 col offset
    const int obase = blockIdx.x * 16;
    const int kbase = wid * 512;

    const int* wrow = wq + (size_t)(obase + srow) * IN_F + kbase + scol;
    // X load base for row-group q2 (rows q2*8 + xr), col kbase + ch*64 + sub*32 + xc
    const float* xb0 = x + (size_t)xr * IN_F + kbase + xc;

    f32x4 acc0 = {0.f, 0.f, 0.f, 0.f};
    f32x4 acc1 = {0.f, 0.f, 0.f, 0.f};

    i32x4 w0[4], w1[4];       // 2-deep W chunk ring
    f32x4 xh0[4], xh1[4];     // 2-deep X half-chunk (sub) buffers

    auto LOADW = [&](i32x4* wbuf, int ch) {
        #pragma unroll
        for (int i = 0; i < 4; ++i)
            wbuf[i] = *(const i32x4*)(wrow + ch * 64 + i * 16);
    };
    auto LOADXH = [&](f32x4* xbuf, int ch, int sub) {
        #pragma unroll
        for (int q2 = 0; q2 < 4; ++q2)
            xbuf[q2] = *(const f32x4*)(xb0 + (size_t)q2 * 8 * IN_F + ch * 64 + sub * 32);
    };
    auto STAGEW = [&](i32x4* wbuf) {
        #pragma unroll
        for (int i = 0; i < 4; ++i) {
            union { fp16x2 v2[2]; half4 v4; } u;
            u.v2[0] = __builtin_amdgcn_cvt_pkrtz((float)wbuf[i][0], (float)wbuf[i][1]);
            u.v2[1] = __builtin_amdgcn_cvt_pkrtz((float)wbuf[i][2], (float)wbuf[i][3]);
            *(half4*)&wlds[wid][srow][scol + i * 16] = u.v4;
        }
    };
    auto STAGEXH = [&](f32x4* xbuf, int sub) {
        #pragma unroll
        for (int q2 = 0; q2 < 4; ++q2) {
            union { fp16x2 v2[2]; half4 v4; } u;
            u.v2[0] = __builtin_amdgcn_cvt_pkrtz(xbuf[q2][0], xbuf[q2][1]);
            u.v2[1] = __builtin_amdgcn_cvt_pkrtz(xbuf[q2][2], xbuf[q2][3]);
            *(half4*)&xlds[wid][q2 * 8 + xr][sub * 32 + xc] = u.v4;
        }
    };
    auto COMPUTE = [&](int sub) {
        half8 wf  = *(half8*)&wlds[wid][c][sub * 32 + kg * 8];
        half8 xf0 = *(half8*)&xlds[wid][c][sub * 32 + kg * 8];
        half8 xf1 = *(half8*)&xlds[wid][16 + c][sub * 32 + kg * 8];
        acc0 = __builtin_amdgcn_mfma_f32_16x16x32_f16(xf0, wf, acc0, 0, 0, 0);
        acc1 = __builtin_amdgcn_mfma_f32_16x16x32_f16(xf1, wf, acc1, 0, 0, 0);
    };

    // prologue: 2 W chunks + first X half in flight
    LOADW(w0, 0); LOADW(w1, 1);
    LOADXH(xh0, 0, 0);

    #pragma unroll
    for (int ch = 0; ch < 8; ++ch) {
        i32x4* wcur = (ch & 1) ? w1 : w0;
        STAGEW(wcur);                       // wlds <- chunk ch
        // sub 0
        LOADXH(xh1, ch, 1);                 // prefetch next half
        STAGEXH(xh0, 0);
        COMPUTE(0);
        // sub 1
        if (ch + 1 < 8) LOADXH(xh0, ch + 1, 0);
        STAGEXH(xh1, 1);
        COMPUTE(1);
        // refill consumed W buffer with chunk ch+2
        if (ch + 2 < 8) LOADW(wcur, ch + 2);
    }

    #pragma unroll
    for (int r = 0; r < 4; ++r) {
        red[wid][lane][r]     = acc0[r];
        red[wid][lane][4 + r] = acc1[r];
    }
    __syncthreads();

    // 512 threads: one (lane, slot) each; sum the 8 wave partials.
    const int rlane = tid & 63;
    const int slot  = tid >> 6;          // 0..7 : (token-half h = slot>>2, reg r = slot&3)
    float s = 0.f;
    #pragma unroll
    for (int wv = 0; wv < 8; ++wv) s += red[wv][rlane][slot];

    const int h = slot >> 2;
    const int r = slot & 3;
    const int t = h * 16 + (rlane >> 4) * 4 + r;   // token
    const int o = obase + (rlane & 15);            // output channel

    out[t * OUT_F + o] = s * scale[o] + bias[o];
}

extern "C" void kernel_launch(void* const* d_in, const int* in_sizes, int n_in,
                              void* d_out, int out_size, void* d_ws, size_t ws_size,
                              hipStream_t stream) {
    const float* x     = (const float*)d_in[0];
    const int*   wq    = (const int*)d_in[1];
    const float* scale = (const float*)d_in[2];
    const float* bias  = (const float*)d_in[3];
    float*       out   = (float*)d_out;

    dql_fused<<<OUT_F / 16, 512, 0, stream>>>(x, wq, scale, bias, out);
}